// Round 6
// baseline (2040.497 us; speedup 1.0000x reference)
//
#include <hip/hip_runtime.h>
#include <hip/hip_bf16.h>
#include <math.h>

#define B_ 2
#define L_ 4096
#define E_ 1024
#define H_ 16
#define D_ 64
#define CHUNK_ 256
#define NC_ 16

// elu(x)+1 : x>0 ? x+1 : exp(x)
__device__ __forceinline__ float fmap1(float x) { return x > 0.f ? x + 1.f : expf(x); }

__device__ __forceinline__ float ldf(const float* p) { return *p; }
__device__ __forceinline__ float ldf(const __hip_bfloat16* p) { return __bfloat162float(*p); }
__device__ __forceinline__ void stv(float* p, float v) { *p = v; }
__device__ __forceinline__ void stv(__hip_bfloat16* p, float v) { *p = __float2bfloat16(v); }

// ---------------------------------------------------------------------------
// C = A * B^T.  A: [M,K] (f32 or bf16), Bw: [N,K] f32. 64x64 tile, BK=16,
// 256 threads, 4x4 patch/thread. TC = bf16 or f32 store.
// EPI=1: qkv epilogue by column block w=n0>>10: w0 fmap*0.125, w1 fmap, w2 raw.
// ---------------------------------------------------------------------------
template<typename TA, typename TC, int EPI>
__global__ __launch_bounds__(256) void gemm_c(const TA* __restrict__ A,
                                              const float* __restrict__ Bw,
                                              TC* __restrict__ C,
                                              int M, int N, int K) {
    __shared__ float As[64][17];   // As[m][k]
    __shared__ float Bs[16][65];   // Bs[k][n]
    const int tid = threadIdx.x;
    const int tx = tid & 15, ty = tid >> 4;
    const int m0 = blockIdx.y * 64, n0 = blockIdx.x * 64;
    const int w = n0 >> 10;
    float acc[4][4] = {};
    for (int kt = 0; kt < K; kt += 16) {
#pragma unroll
        for (int i = 0; i < 4; ++i) {
            int idx = tid + i * 256;
            int r = idx >> 4, cc = idx & 15;
            As[r][cc] = ldf(&A[(size_t)(m0 + r) * K + kt + cc]);
            Bs[cc][r] = Bw[(size_t)(n0 + r) * K + kt + cc];
        }
        __syncthreads();
#pragma unroll
        for (int k = 0; k < 16; ++k) {
            float a[4], bb[4];
#pragma unroll
            for (int i = 0; i < 4; ++i) a[i] = As[ty * 4 + i][k];
#pragma unroll
            for (int j = 0; j < 4; ++j) bb[j] = Bs[k][tx * 4 + j];
#pragma unroll
            for (int i = 0; i < 4; ++i)
#pragma unroll
                for (int j = 0; j < 4; ++j) acc[i][j] += a[i] * bb[j];
        }
        __syncthreads();
    }
#pragma unroll
    for (int i = 0; i < 4; ++i) {
        int row = m0 + ty * 4 + i;
#pragma unroll
        for (int j = 0; j < 4; ++j) {
            int col = n0 + tx * 4 + j;
            float v = acc[i][j];
            if (EPI == 1) {
                if (w == 0)      v = fmap1(v) * 0.125f;
                else if (w == 1) v = fmap1(v);
            }
            stv(&C[(size_t)row * N + col], v);
        }
    }
}

// ---------------------------------------------------------------------------
// Per-chunk state. qv bf16: [B*L, 3*1024], off w*1024+h*64+d (k~ pre-mapped).
// ---------------------------------------------------------------------------
__global__ __launch_bounds__(256) void chunk_state_s(const __hip_bfloat16* __restrict__ qv,
                                                     float* __restrict__ S,
                                                     float* __restrict__ Z) {
    __shared__ float kl[64], vl[64];
    const int c = blockIdx.x, bh = blockIdx.y, b = bh >> 4, h = bh & 15;
    const int tid = threadIdx.x;
    float acc[16];
#pragma unroll
    for (int t = 0; t < 16; ++t) acc[t] = 0.f;
    float zacc = 0.f;
    for (int l = 0; l < CHUNK_; ++l) {
        const __hip_bfloat16* base = qv + (size_t)(b * L_ + c * CHUNK_ + l) * 3072 + h * 64;
        if (tid < 64) kl[tid] = ldf(&base[1024 + tid]);
        else if (tid < 128) vl[tid - 64] = ldf(&base[2048 + (tid - 64)]);
        __syncthreads();
        if (tid < 64) zacc += kl[tid];
#pragma unroll
        for (int t = 0; t < 16; ++t) {
            int pair = tid + t * 256;
            acc[t] += kl[pair >> 6] * vl[pair & 63];
        }
        __syncthreads();
    }
    float* Sp = S + ((size_t)(c * 32 + bh) << 12);
#pragma unroll
    for (int t = 0; t < 16; ++t) Sp[tid + t * 256] = acc[t];
    if (tid < 64) Z[((c * 32 + bh) << 6) + tid] = zacc;
}

__global__ __launch_bounds__(256) void prefix_kernel(float* __restrict__ S,
                                                     float* __restrict__ Z) {
    const int bh = blockIdx.x;
    const int tid = threadIdx.x;
    float run[16];
#pragma unroll
    for (int j = 0; j < 16; ++j) run[j] = 0.f;
    float zrun = 0.f;
    for (int c = 0; c < NC_; ++c) {
        size_t base = ((size_t)(c * 32 + bh) << 12);
#pragma unroll
        for (int j = 0; j < 16; ++j) {
            size_t off = base + tid + j * 256;
            float cur = S[off];
            S[off] = run[j];
            run[j] += cur;
        }
        if (tid < 64) {
            int zoff = ((c * 32 + bh) << 6) + tid;
            float cz = Z[zoff];
            Z[zoff] = zrun;
            zrun += cz;
        }
    }
}

__global__ __launch_bounds__(256) void chunk_out_s(const __hip_bfloat16* __restrict__ qv,
                                                   const float* __restrict__ Spre,
                                                   const float* __restrict__ Zpre,
                                                   __hip_bfloat16* __restrict__ attn) {
    const int c = blockIdx.x, bh = blockIdx.y, b = bh >> 4, h = bh & 15;
    const int tid = threadIdx.x;
    const int gl = c * CHUNK_ + tid;
    const __hip_bfloat16* qp = qv + (size_t)(b * L_ + gl) * 3072 + h * 64;

    float q[64];
#pragma unroll
    for (int d = 0; d < 64; ++d) q[d] = ldf(&qp[d]);

    float num[64];
#pragma unroll
    for (int e = 0; e < 64; ++e) num[e] = 0.f;
    float den = 0.f;

    const float* Sp = Spre + ((size_t)(c * 32 + bh) << 12);
    const float* Zp = Zpre + ((c * 32 + bh) << 6);
    for (int d = 0; d < 64; ++d) {
        float qd = ldf(&qp[d]);
        den += qd * Zp[d];
        const float* srow = Sp + d * 64;
#pragma unroll
        for (int e = 0; e < 64; ++e) num[e] += qd * srow[e];
    }

    for (int m = 0; m <= tid; ++m) {
        const __hip_bfloat16* kp = qv + (size_t)(b * L_ + c * CHUNK_ + m) * 3072 + 1024 + h * 64;
        float s = 0.f;
#pragma unroll
        for (int d = 0; d < 64; ++d) s += q[d] * ldf(&kp[d]);
        den += s;
        const __hip_bfloat16* vp = kp + 1024;
#pragma unroll
        for (int e = 0; e < 64; ++e) num[e] += s * ldf(&vp[e]);
    }

    float inv = 1.f / fmaxf(den, 1e-6f);
    __hip_bfloat16* op = attn + (size_t)(b * L_ + gl) * 1024 + h * 64;
#pragma unroll
    for (int e = 0; e < 64; ++e) op[e] = __float2bfloat16(num[e] * inv);
}

// ---------------------------------------------------------------------------
extern "C" void kernel_launch(void* const* d_in, const int* in_sizes, int n_in,
                              void* d_out, int out_size, void* d_ws, size_t ws_size,
                              hipStream_t stream) {
    (void)ws_size; (void)out_size;
    // Input identification by flat size (robust to pointer order).
    const float *x = nullptr, *Wqkv = nullptr, *Wout = nullptr;
    for (int i = 0; i < n_in; ++i) {
        if (in_sizes[i] == 8388608)      x    = (const float*)d_in[i];
        else if (in_sizes[i] == 3145728) Wqkv = (const float*)d_in[i];
        else if (in_sizes[i] == 1048576) Wout = (const float*)d_in[i];
    }

    __hip_bfloat16* ws16 = (__hip_bfloat16*)d_ws;
    __hip_bfloat16* qv   = ws16;                        // 25165824 bf16 (48 MB)
    __hip_bfloat16* attn = ws16 + 25165824;             //  8388608 bf16 (16 MB)
    float* S = (float*)(ws16 + 25165824 + 8388608);     // 2097152 f32 (8 MB)
    float* Z = S + 2097152;                             //   32768 f32

    // 1. qv = feature_map(x @ W_qkv^T): q~ = fmap*0.125, k~ = fmap, v raw
    gemm_c<float, __hip_bfloat16, 1><<<dim3(3072 / 64, 8192 / 64), 256, 0, stream>>>(
        x, Wqkv, qv, B_ * L_, 3 * E_, E_);
    // 2. per-chunk states
    chunk_state_s<<<dim3(NC_, B_ * H_), 256, 0, stream>>>(qv, S, Z);
    // 3. exclusive prefix over chunks
    prefix_kernel<<<B_ * H_, 256, 0, stream>>>(S, Z);
    // 4. per-row causal output -> attn bf16
    chunk_out_s<<<dim3(NC_, B_ * H_), 256, 0, stream>>>(qv, S, Z, attn);
    // 5. out = attn @ W_out^T, FULL f32 store (d_out is float32 — round-5 probe)
    gemm_c<__hip_bfloat16, float, 0><<<dim3(1024 / 64, 8192 / 64), 256, 0, stream>>>(
        attn, Wout, (float*)d_out, B_ * L_, E_, E_);
}

// Round 7
// 862.552 us; speedup vs baseline: 2.3657x; 2.3657x over previous
//
#include <hip/hip_runtime.h>
#include <hip/hip_bf16.h>
#include <math.h>

#define B_ 2
#define L_ 4096
#define E_ 1024
#define H_ 16
#define D_ 64
#define CHUNK_ 256
#define NC_ 16

typedef __bf16 bf16x8 __attribute__((ext_vector_type(8)));
typedef float  f32x4  __attribute__((ext_vector_type(4)));

// elu(x)+1 : x>0 ? x+1 : exp(x)
__device__ __forceinline__ float fmap1(float x) { return x > 0.f ? x + 1.f : expf(x); }
__device__ __forceinline__ float ldf(const __hip_bfloat16* p) { return __bfloat162float(*p); }

// async global->LDS, 16B per lane; LDS dest = wave-uniform base + lane*16
__device__ __forceinline__ void async16(const __bf16* g, __bf16* lds) {
    __builtin_amdgcn_global_load_lds(
        (const __attribute__((address_space(1))) void*)g,
        (__attribute__((address_space(3))) void*)lds,
        16, 0, 0);
}

// ---------------------------------------------------------------------------
// f32 -> bf16 cast, 4 elems/thread
// ---------------------------------------------------------------------------
__global__ __launch_bounds__(256) void cast_f32_bf16(const float* __restrict__ in,
                                                     __hip_bfloat16* __restrict__ out, int n) {
    int i = (blockIdx.x * 256 + threadIdx.x) << 2;
    if (i < n) {
        float4 v = *(const float4*)(in + i);
        __hip_bfloat16 a = __float2bfloat16(v.x), b = __float2bfloat16(v.y),
                       c = __float2bfloat16(v.z), d = __float2bfloat16(v.w);
        ushort4 o;
        o.x = *(unsigned short*)&a; o.y = *(unsigned short*)&b;
        o.z = *(unsigned short*)&c; o.w = *(unsigned short*)&d;
        *(ushort4*)(out + i) = o;
    }
}

// ---------------------------------------------------------------------------
// MFMA bf16 GEMM: C = A * Bw^T.  A:[M,K] bf16, Bw:[N,K] bf16 (both row-major,
// K contiguous). 128x128 block tile, BK=32, 256 thr = 4 waves in 2x2; each
// wave 64x64 via 4x4 mfma_f32_16x16x32_bf16. m97 structure: global_load_lds
// width=16 staging + 2-barrier K-loop.
// EPI=0: f32 store. EPI=1: qkv epilogue by col block w=n0>>10
//   (w0: fmap*0.125 -> q~, w1: fmap -> k~, w2: raw v), bf16 store.
// ---------------------------------------------------------------------------
template<int EPI>
__global__ __launch_bounds__(256) void gemm_mfma(const __bf16* __restrict__ A,
                                                 const __bf16* __restrict__ Bw,
                                                 void* __restrict__ Cv,
                                                 int M, int N, int K) {
    __shared__ alignas(16) __bf16 As[128 * 32];
    __shared__ alignas(16) __bf16 Bs[128 * 32];
    const int tid = threadIdx.x;
    const int wave = tid >> 6, lane = tid & 63;
    const int wm = wave >> 1, wn = wave & 1;
    const int lq = lane >> 4, lr = lane & 15;
    const int m0 = blockIdx.y * 128, n0 = blockIdx.x * 128;

    f32x4 acc[4][4];
#pragma unroll
    for (int i = 0; i < 4; ++i)
#pragma unroll
        for (int j = 0; j < 4; ++j) acc[i][j] = (f32x4){0.f, 0.f, 0.f, 0.f};

    // staging: 8 chunks of 16 rows x 32 cols per tile; wave handles chunks
    // {wave, wave+4}. lane -> row lane>>2 within chunk, 8-elem col block lane&3.
    const int stg_r = lane >> 2;
    const int stg_c = (lane & 3) << 3;
    const __bf16* Ag0 = A + (size_t)(m0 + (wave << 4) + stg_r) * K + stg_c;
    const __bf16* Ag1 = A + (size_t)(m0 + 64 + (wave << 4) + stg_r) * K + stg_c;
    const __bf16* Bg0 = Bw + (size_t)(n0 + (wave << 4) + stg_r) * K + stg_c;
    const __bf16* Bg1 = Bw + (size_t)(n0 + 64 + (wave << 4) + stg_r) * K + stg_c;
    __bf16* Al0 = As + (wave << 9);
    __bf16* Al1 = As + ((wave + 4) << 9);
    __bf16* Bl0 = Bs + (wave << 9);
    __bf16* Bl1 = Bs + ((wave + 4) << 9);

    for (int kt = 0; kt < K; kt += 32) {
        __syncthreads();                      // prev consumers done
        async16(Ag0 + kt, Al0);
        async16(Ag1 + kt, Al1);
        async16(Bg0 + kt, Bl0);
        async16(Bg1 + kt, Bl1);
        __syncthreads();                      // vmcnt(0) drain + barrier
        bf16x8 af[4], bfr[4];
#pragma unroll
        for (int t = 0; t < 4; ++t) {
            af[t]  = *(const bf16x8*)&As[((wm << 6) + (t << 4) + lr) * 32 + (lq << 3)];
            bfr[t] = *(const bf16x8*)&Bs[((wn << 6) + (t << 4) + lr) * 32 + (lq << 3)];
        }
#pragma unroll
        for (int mt = 0; mt < 4; ++mt)
#pragma unroll
            for (int nt = 0; nt < 4; ++nt)
                acc[mt][nt] = __builtin_amdgcn_mfma_f32_16x16x32_bf16(
                    af[mt], bfr[nt], acc[mt][nt], 0, 0, 0);
    }

    // C/D layout (m89/m91 verified): col = lane&15, row = (lane>>4)*4 + reg
    const int w = n0 >> 10;
#pragma unroll
    for (int mt = 0; mt < 4; ++mt) {
#pragma unroll
        for (int nt = 0; nt < 4; ++nt) {
            int m = m0 + (wm << 6) + (mt << 4) + (lq << 2);
            int n = n0 + (wn << 6) + (nt << 4) + lr;
#pragma unroll
            for (int r = 0; r < 4; ++r) {
                float v = acc[mt][nt][r];
                if (EPI == 1) {
                    if (w == 0)      v = fmap1(v) * 0.125f;
                    else if (w == 1) v = fmap1(v);
                    ((__hip_bfloat16*)Cv)[(size_t)(m + r) * N + n] = __float2bfloat16(v);
                } else {
                    ((float*)Cv)[(size_t)(m + r) * N + n] = v;
                }
            }
        }
    }
}

// ---------------------------------------------------------------------------
// Per-chunk state. qv bf16: [B*L, 3*1024], off w*1024+h*64+d (k~ pre-mapped).
// ---------------------------------------------------------------------------
__global__ __launch_bounds__(256) void chunk_state_s(const __hip_bfloat16* __restrict__ qv,
                                                     float* __restrict__ S,
                                                     float* __restrict__ Z) {
    __shared__ float kl[64], vl[64];
    const int c = blockIdx.x, bh = blockIdx.y, b = bh >> 4, h = bh & 15;
    const int tid = threadIdx.x;
    float acc[16];
#pragma unroll
    for (int t = 0; t < 16; ++t) acc[t] = 0.f;
    float zacc = 0.f;
    for (int l = 0; l < CHUNK_; ++l) {
        const __hip_bfloat16* base = qv + (size_t)(b * L_ + c * CHUNK_ + l) * 3072 + h * 64;
        if (tid < 64) kl[tid] = ldf(&base[1024 + tid]);
        else if (tid < 128) vl[tid - 64] = ldf(&base[2048 + (tid - 64)]);
        __syncthreads();
        if (tid < 64) zacc += kl[tid];
#pragma unroll
        for (int t = 0; t < 16; ++t) {
            int pair = tid + t * 256;
            acc[t] += kl[pair >> 6] * vl[pair & 63];
        }
        __syncthreads();
    }
    float* Sp = S + ((size_t)(c * 32 + bh) << 12);
#pragma unroll
    for (int t = 0; t < 16; ++t) Sp[tid + t * 256] = acc[t];
    if (tid < 64) Z[((c * 32 + bh) << 6) + tid] = zacc;
}

__global__ __launch_bounds__(256) void prefix_kernel(float* __restrict__ S,
                                                     float* __restrict__ Z) {
    const int bh = blockIdx.x;
    const int tid = threadIdx.x;
    float run[16];
#pragma unroll
    for (int j = 0; j < 16; ++j) run[j] = 0.f;
    float zrun = 0.f;
    for (int c = 0; c < NC_; ++c) {
        size_t base = ((size_t)(c * 32 + bh) << 12);
#pragma unroll
        for (int j = 0; j < 16; ++j) {
            size_t off = base + tid + j * 256;
            float cur = S[off];
            S[off] = run[j];
            run[j] += cur;
        }
        if (tid < 64) {
            int zoff = ((c * 32 + bh) << 6) + tid;
            float cz = Z[zoff];
            Z[zoff] = zrun;
            zrun += cz;
        }
    }
}

__global__ __launch_bounds__(256) void chunk_out_s(const __hip_bfloat16* __restrict__ qv,
                                                   const float* __restrict__ Spre,
                                                   const float* __restrict__ Zpre,
                                                   __hip_bfloat16* __restrict__ attn) {
    const int c = blockIdx.x, bh = blockIdx.y, b = bh >> 4, h = bh & 15;
    const int tid = threadIdx.x;
    const int gl = c * CHUNK_ + tid;
    const __hip_bfloat16* qp = qv + (size_t)(b * L_ + gl) * 3072 + h * 64;

    float q[64];
#pragma unroll
    for (int d = 0; d < 64; ++d) q[d] = ldf(&qp[d]);

    float num[64];
#pragma unroll
    for (int e = 0; e < 64; ++e) num[e] = 0.f;
    float den = 0.f;

    const float* Sp = Spre + ((size_t)(c * 32 + bh) << 12);
    const float* Zp = Zpre + ((c * 32 + bh) << 6);
    for (int d = 0; d < 64; ++d) {
        float qd = ldf(&qp[d]);
        den += qd * Zp[d];
        const float* srow = Sp + d * 64;
#pragma unroll
        for (int e = 0; e < 64; ++e) num[e] += qd * srow[e];
    }

    for (int m = 0; m <= tid; ++m) {
        const __hip_bfloat16* kp = qv + (size_t)(b * L_ + c * CHUNK_ + m) * 3072 + 1024 + h * 64;
        float s = 0.f;
#pragma unroll
        for (int d = 0; d < 64; ++d) s += q[d] * ldf(&kp[d]);
        den += s;
        const __hip_bfloat16* vp = kp + 1024;
#pragma unroll
        for (int e = 0; e < 64; ++e) num[e] += s * ldf(&vp[e]);
    }

    float inv = 1.f / fmaxf(den, 1e-6f);
    __hip_bfloat16* op = attn + (size_t)(b * L_ + gl) * 1024 + h * 64;
#pragma unroll
    for (int e = 0; e < 64; ++e) op[e] = __float2bfloat16(num[e] * inv);
}

// ---------------------------------------------------------------------------
extern "C" void kernel_launch(void* const* d_in, const int* in_sizes, int n_in,
                              void* d_out, int out_size, void* d_ws, size_t ws_size,
                              hipStream_t stream) {
    (void)ws_size; (void)out_size;
    const float *x = nullptr, *Wqkv = nullptr, *Wout = nullptr;
    for (int i = 0; i < n_in; ++i) {
        if (in_sizes[i] == 8388608)      x    = (const float*)d_in[i];
        else if (in_sizes[i] == 3145728) Wqkv = (const float*)d_in[i];
        else if (in_sizes[i] == 1048576) Wout = (const float*)d_in[i];
    }

    // workspace: 96.1 MB (<= the 142.7 MB layout known to fit)
    __hip_bfloat16* ws16  = (__hip_bfloat16*)d_ws;
    __hip_bfloat16* xb    = ws16;                    //  8388608 bf16
    __hip_bfloat16* Wqkvb = xb + 8388608;            //  3145728
    __hip_bfloat16* Woutb = Wqkvb + 3145728;         //  1048576
    __hip_bfloat16* qv    = Woutb + 1048576;         // 25165824
    __hip_bfloat16* attn  = qv + 25165824;           //  8388608
    float* S = (float*)(attn + 8388608);             //  2097152 f32
    float* Z = S + 2097152;                          //    32768 f32

    // 0. casts f32 -> bf16
    cast_f32_bf16<<<8388608 / 1024, 256, 0, stream>>>(x, xb, 8388608);
    cast_f32_bf16<<<3145728 / 1024, 256, 0, stream>>>(Wqkv, Wqkvb, 3145728);
    cast_f32_bf16<<<1048576 / 1024, 256, 0, stream>>>(Wout, Woutb, 1048576);

    // 1. qv = feature_map(xb @ Wqkvb^T)  [8192 x 3072] bf16, MFMA
    gemm_mfma<1><<<dim3(3072 / 128, 8192 / 128), 256, 0, stream>>>(
        (const __bf16*)xb, (const __bf16*)Wqkvb, qv, B_ * L_, 3 * E_, E_);
    // 2. per-chunk states
    chunk_state_s<<<dim3(NC_, B_ * H_), 256, 0, stream>>>(qv, S, Z);
    // 3. exclusive prefix over chunks
    prefix_kernel<<<B_ * H_, 256, 0, stream>>>(S, Z);
    // 4. per-row causal output -> attn bf16
    chunk_out_s<<<dim3(NC_, B_ * H_), 256, 0, stream>>>(qv, S, Z, attn);
    // 5. out = attn @ Woutb^T  [8192 x 1024] f32, MFMA
    gemm_mfma<0><<<dim3(1024 / 128, 8192 / 128), 256, 0, stream>>>(
        (const __bf16*)attn, (const __bf16*)Woutb, d_out, B_ * L_, E_, E_);
}

// Round 8
// 285.778 us; speedup vs baseline: 7.1401x; 3.0183x over previous
//
#include <hip/hip_runtime.h>
#include <hip/hip_bf16.h>
#include <math.h>

#define B_ 2
#define L_ 4096
#define E_ 1024
#define H_ 16
#define D_ 64
#define CK_ 64     // chunk size for state/scan granularity
#define NC_ 64

typedef __bf16 bf16x8 __attribute__((ext_vector_type(8)));
typedef __bf16 bf16x4 __attribute__((ext_vector_type(4)));
typedef float  f32x4  __attribute__((ext_vector_type(4)));

__device__ __forceinline__ float fmap1(float x) { return x > 0.f ? x + 1.f : expf(x); }
__device__ __forceinline__ float ldf(const __hip_bfloat16* p) { return __bfloat162float(*p); }
__device__ __forceinline__ __bf16 f2b(float f) {
    __hip_bfloat16 h = __float2bfloat16(f); return *reinterpret_cast<__bf16*>(&h);
}
__device__ __forceinline__ unsigned short f2u(float f) {
    __hip_bfloat16 h = __float2bfloat16(f); return *reinterpret_cast<unsigned short*>(&h);
}

union U8 { bf16x8 v; __bf16 e[8]; bf16x4 half2[2]; };

// async global->LDS, 16B per lane
__device__ __forceinline__ void async16(const __bf16* g, __bf16* lds) {
    __builtin_amdgcn_global_load_lds(
        (const __attribute__((address_space(1))) void*)g,
        (__attribute__((address_space(3))) void*)lds, 16, 0, 0);
}

// ---------------------------------------------------------------------------
__global__ __launch_bounds__(256) void cast_f32_bf16(const float* __restrict__ in,
                                                     __hip_bfloat16* __restrict__ out, int n) {
    int i = (blockIdx.x * 256 + threadIdx.x) << 2;
    if (i < n) {
        float4 v = *(const float4*)(in + i);
        ushort4 o = {f2u(v.x), f2u(v.y), f2u(v.z), f2u(v.w)};
        *(ushort4*)(out + i) = o;
    }
}

// ---------------------------------------------------------------------------
// MFMA bf16 GEMM: C = A*Bw^T (A:[M,K], Bw:[N,K] bf16). 128x128, BK=32,
// 4 waves 2x2, 4x4 16x16x32 per wave. EPI=1: qkv epilogue (w=n>>10:
// q~=fmap*0.125, k~=fmap, v raw) to natural [M,3072] bf16, PLUS transposed
// V^T [b,h,e,4096] bf16 for w==2. EPI=0: plain f32 store.
// ---------------------------------------------------------------------------
template<int EPI>
__global__ __launch_bounds__(256) void gemm_mfma(const __bf16* __restrict__ A,
                                                 const __bf16* __restrict__ Bw,
                                                 void* __restrict__ Cv,
                                                 __hip_bfloat16* __restrict__ VT,
                                                 int M, int N, int K) {
    __shared__ alignas(16) __bf16 As[128 * 32];
    __shared__ alignas(16) __bf16 Bs[128 * 32];
    const int tid = threadIdx.x;
    const int wave = tid >> 6, lane = tid & 63;
    const int wm = wave >> 1, wn = wave & 1;
    const int lq = lane >> 4, lr = lane & 15;
    const int m0 = blockIdx.y * 128, n0 = blockIdx.x * 128;

    f32x4 acc[4][4];
#pragma unroll
    for (int i = 0; i < 4; ++i)
#pragma unroll
        for (int j = 0; j < 4; ++j) acc[i][j] = (f32x4){0.f, 0.f, 0.f, 0.f};

    const int stg_r = lane >> 2, stg_c = (lane & 3) << 3;
    const __bf16* Ag0 = A + (size_t)(m0 + (wave << 4) + stg_r) * K + stg_c;
    const __bf16* Ag1 = A + (size_t)(m0 + 64 + (wave << 4) + stg_r) * K + stg_c;
    const __bf16* Bg0 = Bw + (size_t)(n0 + (wave << 4) + stg_r) * K + stg_c;
    const __bf16* Bg1 = Bw + (size_t)(n0 + 64 + (wave << 4) + stg_r) * K + stg_c;
    __bf16* Al0 = As + (wave << 9);
    __bf16* Al1 = As + ((wave + 4) << 9);
    __bf16* Bl0 = Bs + (wave << 9);
    __bf16* Bl1 = Bs + ((wave + 4) << 9);

    for (int kt = 0; kt < K; kt += 32) {
        __syncthreads();
        async16(Ag0 + kt, Al0);
        async16(Ag1 + kt, Al1);
        async16(Bg0 + kt, Bl0);
        async16(Bg1 + kt, Bl1);
        __syncthreads();
        bf16x8 af[4], bfr[4];
#pragma unroll
        for (int t = 0; t < 4; ++t) {
            af[t]  = *(const bf16x8*)&As[((wm << 6) + (t << 4) + lr) * 32 + (lq << 3)];
            bfr[t] = *(const bf16x8*)&Bs[((wn << 6) + (t << 4) + lr) * 32 + (lq << 3)];
        }
#pragma unroll
        for (int mt = 0; mt < 4; ++mt)
#pragma unroll
            for (int nt = 0; nt < 4; ++nt)
                acc[mt][nt] = __builtin_amdgcn_mfma_f32_16x16x32_bf16(
                    af[mt], bfr[nt], acc[mt][nt], 0, 0, 0);
    }

#pragma unroll
    for (int mt = 0; mt < 4; ++mt) {
#pragma unroll
        for (int nt = 0; nt < 4; ++nt) {
            int m = m0 + (wm << 6) + (mt << 4) + (lq << 2);
            int n = n0 + (wn << 6) + (nt << 4) + lr;
            if (EPI == 1) {
                int w = n >> 10, hh = (n >> 6) & 15, dd = n & 63;
                float vv[4];
#pragma unroll
                for (int r = 0; r < 4; ++r) {
                    float v = acc[mt][nt][r];
                    if (w == 0)      v = fmap1(v) * 0.125f;
                    else if (w == 1) v = fmap1(v);
                    vv[r] = v;
                    ((__hip_bfloat16*)Cv)[(size_t)(m + r) * N + n] = __float2bfloat16(v);
                }
                if (w == 2) {   // also V^T [ (b*16+h)*64 + e ][4096]
                    int b = m >> 12, l = m & 4095;
                    ushort4 u = {f2u(vv[0]), f2u(vv[1]), f2u(vv[2]), f2u(vv[3])};
                    *(ushort4*)&VT[((size_t)((b * 16 + hh) * 64 + dd) << 12) + l] = u;
                }
            } else {
#pragma unroll
                for (int r = 0; r < 4; ++r)
                    ((float*)Cv)[(size_t)(m + r) * N + n] = acc[mt][nt][r];
            }
        }
    }
}

// ---------------------------------------------------------------------------
// Per-chunk (CK=64) state, stored TRANSPOSED:  S_T[e][d] = sum_l v[l][e]*k~[l][d]
// Z[d] = sum_l k~[l][d].  grid (64, 32).
// ---------------------------------------------------------------------------
__global__ __launch_bounds__(256) void chunk_state64(const __hip_bfloat16* __restrict__ qv,
                                                     float* __restrict__ S,
                                                     float* __restrict__ Z) {
    __shared__ float kl[64], vl[64];
    const int c = blockIdx.x, bh = blockIdx.y, b = bh >> 4, h = bh & 15;
    const int tid = threadIdx.x;
    float acc[16];
#pragma unroll
    for (int t = 0; t < 16; ++t) acc[t] = 0.f;
    float zacc = 0.f;
    for (int l = 0; l < CK_; ++l) {
        const __hip_bfloat16* base = qv + (size_t)(b * L_ + c * CK_ + l) * 3072 + h * 64;
        if (tid < 64) kl[tid] = ldf(&base[1024 + tid]);
        else if (tid < 128) vl[tid - 64] = ldf(&base[2048 + (tid - 64)]);
        __syncthreads();
        if (tid < 64) zacc += kl[tid];
#pragma unroll
        for (int t = 0; t < 16; ++t) {
            int pair = tid + t * 256;              // pair = e*64 + d
            acc[t] += vl[pair >> 6] * kl[pair & 63];
        }
        __syncthreads();
    }
    float* Sp = S + ((size_t)(c * 32 + bh) << 12);
#pragma unroll
    for (int t = 0; t < 16; ++t) Sp[tid + t * 256] = acc[t];
    if (tid < 64) Z[((c * 32 + bh) << 6) + tid] = zacc;
}

// ---------------------------------------------------------------------------
// Exclusive prefix over 64 chunks, element-parallel. grid (16, 32).
// ---------------------------------------------------------------------------
__global__ __launch_bounds__(256) void prefix64(float* __restrict__ S,
                                                float* __restrict__ Z) {
    const int bh = blockIdx.y;
    const int idx = blockIdx.x * 256 + threadIdx.x;   // 0..4095
    float run = 0.f;
    for (int c = 0; c < NC_; ++c) {
        size_t off = ((size_t)(c * 32 + bh) << 12) + idx;
        float cur = S[off];
        S[off] = run;
        run += cur;
    }
    if (blockIdx.x == 0 && threadIdx.x < 64) {
        float zr = 0.f;
        for (int c = 0; c < NC_; ++c) {
            int zoff = ((c * 32 + bh) << 6) + threadIdx.x;
            float cz = Z[zoff];
            Z[zoff] = zr;
            zr += cz;
        }
    }
}

// ---------------------------------------------------------------------------
// MFMA attention output. grid (16, 32) x 256thr; wave w owns chunk
// c = bx*4+w of (b,h)=by. num = Q@Spre + causal(QK^T)@V ; den via
// B=Zp-broadcast and B=ones fragments. All operands read direct from global;
// P round-trips LDS (transposed-compute -> b64 packed natural store).
// ---------------------------------------------------------------------------
__global__ __launch_bounds__(256) void attn_out_mfma(const __hip_bfloat16* __restrict__ qvh,
                                                     const float* __restrict__ S,
                                                     const float* __restrict__ Z,
                                                     const __hip_bfloat16* __restrict__ VTh,
                                                     __hip_bfloat16* __restrict__ attn) {
    __shared__ __bf16 Pbuf[4 * 64 * 68];
    const int tid = threadIdx.x, wave = tid >> 6, lane = tid & 63;
    const int quad = lane >> 4, lr = lane & 15;
    const int bh = blockIdx.y, b = bh >> 4, h = bh & 15;
    const int c = blockIdx.x * 4 + wave;
    const size_t t0 = (size_t)b * L_ + c * CK_;
    const __bf16* qb = (const __bf16*)qvh;
    const __bf16* VT = (const __bf16*)VTh;
    __bf16* P = Pbuf + wave * (64 * 68);

    // Q fragments: A[l = ls*16+lr][d = kk*32+quad*8+j]
    bf16x8 qf[4][2];
#pragma unroll
    for (int ls = 0; ls < 4; ++ls)
#pragma unroll
        for (int kk = 0; kk < 2; ++kk)
            qf[ls][kk] = *(const bf16x8*)&qb[(t0 + ls * 16 + lr) * 3072 + h * 64 + kk * 32 + quad * 8];

    f32x4 num[4][4], den[4];
#pragma unroll
    for (int i = 0; i < 4; ++i) {
        den[i] = (f32x4){0.f, 0.f, 0.f, 0.f};
#pragma unroll
        for (int j = 0; j < 4; ++j) num[i][j] = (f32x4){0.f, 0.f, 0.f, 0.f};
    }

    // den init: B[n][k=d] = Zp[d]
    const float* Zp = Z + ((size_t)(c * 32 + bh) << 6);
    U8 zf[2];
#pragma unroll
    for (int kk = 0; kk < 2; ++kk)
#pragma unroll
        for (int j = 0; j < 8; ++j) zf[kk].e[j] = f2b(Zp[kk * 32 + quad * 8 + j]);
#pragma unroll
    for (int ls = 0; ls < 4; ++ls)
#pragma unroll
        for (int kk = 0; kk < 2; ++kk)
            den[ls] = __builtin_amdgcn_mfma_f32_16x16x32_bf16(qf[ls][kk], zf[kk].v, den[ls], 0, 0, 0);

    // num init: Q @ Spre  (B[e][k=d] = S_T[e][d], f32 -> bf16)
    const float* Sp = S + ((size_t)(c * 32 + bh) << 12);
#pragma unroll
    for (int es = 0; es < 4; ++es) {
        U8 sf[2];
#pragma unroll
        for (int kk = 0; kk < 2; ++kk) {
            const float* p = &Sp[(es * 16 + lr) * 64 + kk * 32 + quad * 8];
#pragma unroll
            for (int j = 0; j < 8; ++j) sf[kk].e[j] = f2b(p[j]);
        }
#pragma unroll
        for (int ls = 0; ls < 4; ++ls)
#pragma unroll
            for (int kk = 0; kk < 2; ++kk)
                num[ls][es] = __builtin_amdgcn_mfma_f32_16x16x32_bf16(
                    qf[ls][kk], sf[kk].v, num[ls][es], 0, 0, 0);
    }

    // K fragments
    bf16x8 kf[4][2];
#pragma unroll
    for (int ms = 0; ms < 4; ++ms)
#pragma unroll
        for (int kk = 0; kk < 2; ++kk)
            kf[ms][kk] = *(const bf16x8*)&qb[(t0 + ms * 16 + lr) * 3072 + 1024 + h * 64 + kk * 32 + quad * 8];

    // P^T = K·Q^T -> D[m][l]; transpose-store natural P[l][m] as packed b64.
#pragma unroll
    for (int ls = 0; ls < 4; ++ls) {
#pragma unroll
        for (int ms = 0; ms < 4; ++ms) {
            int off = (ls * 16 + lr) * 68 + ms * 16 + quad * 4;
            if (ms <= ls) {
                f32x4 pt = (f32x4){0.f, 0.f, 0.f, 0.f};
                pt = __builtin_amdgcn_mfma_f32_16x16x32_bf16(kf[ms][0], qf[ls][0], pt, 0, 0, 0);
                pt = __builtin_amdgcn_mfma_f32_16x16x32_bf16(kf[ms][1], qf[ls][1], pt, 0, 0, 0);
                ushort4 u;
                if (ms == ls) {   // causal: zero where m > l ; m=quad*4+r, l=lr
                    u.x = (quad * 4 + 0 > lr) ? 0 : f2u(pt[0]);
                    u.y = (quad * 4 + 1 > lr) ? 0 : f2u(pt[1]);
                    u.z = (quad * 4 + 2 > lr) ? 0 : f2u(pt[2]);
                    u.w = (quad * 4 + 3 > lr) ? 0 : f2u(pt[3]);
                } else {
                    u = (ushort4){f2u(pt[0]), f2u(pt[1]), f2u(pt[2]), f2u(pt[3])};
                }
                *(ushort4*)&P[off] = u;
            } else {
                *(ushort4*)&P[off] = (ushort4){0, 0, 0, 0};
            }
        }
    }

    // ones fragment
    U8 of;
#pragma unroll
    for (int j = 0; j < 8; ++j) of.e[j] = f2b(1.0f);

    // PV: num += P@V (B = V^T[e][m]), den += rowsum(P) via ones
#pragma unroll
    for (int kk = 0; kk < 2; ++kk) {
        U8 pf[4];
#pragma unroll
        for (int ls = 0; ls < 4; ++ls) {
            pf[ls].half2[0] = *(const bf16x4*)&P[(ls * 16 + lr) * 68 + kk * 32 + quad * 8];
            pf[ls].half2[1] = *(const bf16x4*)&P[(ls * 16 + lr) * 68 + kk * 32 + quad * 8 + 4];
        }
        bf16x8 vf[4];
#pragma unroll
        for (int es = 0; es < 4; ++es)
            vf[es] = *(const bf16x8*)&VT[((size_t)((b * 16 + h) * 64 + es * 16 + lr) << 12)
                                         + c * CK_ + kk * 32 + quad * 8];
#pragma unroll
        for (int ls = 0; ls < 4; ++ls) {
            den[ls] = __builtin_amdgcn_mfma_f32_16x16x32_bf16(pf[ls].v, of.v, den[ls], 0, 0, 0);
#pragma unroll
            for (int es = 0; es < 4; ++es)
                num[ls][es] = __builtin_amdgcn_mfma_f32_16x16x32_bf16(
                    pf[ls].v, vf[es], num[ls][es], 0, 0, 0);
        }
    }

    // epilogue: attn[l][h*64+e] = num/max(den,1e-6)
#pragma unroll
    for (int ls = 0; ls < 4; ++ls) {
#pragma unroll
        for (int r = 0; r < 4; ++r) {
            float inv = 1.f / fmaxf(den[ls][r], 1e-6f);
            size_t row = (t0 + ls * 16 + quad * 4 + r) * 1024 + h * 64;
#pragma unroll
            for (int es = 0; es < 4; ++es)
                attn[row + es * 16 + lr] = __float2bfloat16(num[ls][es][r] * inv);
        }
    }
}

// ---------------------------------------------------------------------------
extern "C" void kernel_launch(void* const* d_in, const int* in_sizes, int n_in,
                              void* d_out, int out_size, void* d_ws, size_t ws_size,
                              hipStream_t stream) {
    (void)ws_size; (void)out_size;
    const float *x = nullptr, *Wqkv = nullptr, *Wout = nullptr;
    for (int i = 0; i < n_in; ++i) {
        if (in_sizes[i] == 8388608)      x    = (const float*)d_in[i];
        else if (in_sizes[i] == 3145728) Wqkv = (const float*)d_in[i];
        else if (in_sizes[i] == 1048576) Wout = (const float*)d_in[i];
    }

    // ws layout (bf16 elements). attn aliases xb (dead after GEMM1). 124.8MB total.
    __hip_bfloat16* ws16  = (__hip_bfloat16*)d_ws;
    __hip_bfloat16* xb    = ws16;                       //  8388608 (attn aliases)
    __hip_bfloat16* attn  = ws16;
    __hip_bfloat16* Wqkvb = ws16 + 8388608;             //  3145728
    __hip_bfloat16* Woutb = Wqkvb + 3145728;            //  1048576
    __hip_bfloat16* qv    = Woutb + 1048576;            // 25165824 (q~,k~,v natural)
    __hip_bfloat16* VT    = qv + 25165824;              //  8388608 (v transposed)
    float* S = (float*)(VT + 8388608);                  //  8388608 f32 (S_T per chunk)
    float* Z = S + 8388608;                             //   131072 f32

    cast_f32_bf16<<<8388608 / 1024, 256, 0, stream>>>(x, xb, 8388608);
    cast_f32_bf16<<<3145728 / 1024, 256, 0, stream>>>(Wqkv, Wqkvb, 3145728);
    cast_f32_bf16<<<1048576 / 1024, 256, 0, stream>>>(Wout, Woutb, 1048576);

    // 1. qv (+VT) = feature_map(xb @ Wqkvb^T)
    gemm_mfma<1><<<dim3(3072 / 128, 8192 / 128), 256, 0, stream>>>(
        (const __bf16*)xb, (const __bf16*)Wqkvb, qv, VT, B_ * L_, 3 * E_, E_);
    // 2. per-chunk transposed states (CK=64)
    chunk_state64<<<dim3(NC_, B_ * H_), 256, 0, stream>>>(qv, S, Z);
    // 3. exclusive prefix over 64 chunks
    prefix64<<<dim3(16, B_ * H_), 256, 0, stream>>>(S, Z);
    // 4. MFMA attention output -> attn bf16
    attn_out_mfma<<<dim3(16, B_ * H_), 256, 0, stream>>>(qv, S, Z, VT, attn);
    // 5. out = attn @ Woutb^T, f32
    gemm_mfma<0><<<dim3(1024 / 128, 8192 / 128), 256, 0, stream>>>(
        (const __bf16*)attn, (const __bf16*)Woutb, d_out, nullptr, B_ * L_, E_, E_);
}

// Round 9
// 250.980 us; speedup vs baseline: 8.1301x; 1.1387x over previous
//
#include <hip/hip_runtime.h>
#include <hip/hip_bf16.h>
#include <math.h>

#define B_ 2
#define L_ 4096
#define E_ 1024
#define H_ 16
#define D_ 64
#define CK_ 64
#define NC_ 64

typedef __bf16 bf16x8 __attribute__((ext_vector_type(8)));
typedef __bf16 bf16x4 __attribute__((ext_vector_type(4)));
typedef float  f32x4  __attribute__((ext_vector_type(4)));

__device__ __forceinline__ float fmap1(float x) { return x > 0.f ? x + 1.f : expf(x); }
__device__ __forceinline__ float b2f(__bf16 v) {
    __hip_bfloat16 h = *reinterpret_cast<__hip_bfloat16*>(&v); return __bfloat162float(h);
}
__device__ __forceinline__ __bf16 f2b(float f) {
    __hip_bfloat16 h = __float2bfloat16(f); return *reinterpret_cast<__bf16*>(&h);
}
__device__ __forceinline__ unsigned short f2u(float f) {
    __hip_bfloat16 h = __float2bfloat16(f); return *reinterpret_cast<unsigned short*>(&h);
}

union U8 { bf16x8 v; __bf16 e[8]; bf16x4 half2[2]; };

__device__ __forceinline__ void async16(const __bf16* g, __bf16* lds) {
    __builtin_amdgcn_global_load_lds(
        (const __attribute__((address_space(1))) void*)g,
        (__attribute__((address_space(3))) void*)lds, 16, 0, 0);
}

// ---------------------------------------------------------------------------
__global__ __launch_bounds__(256) void cast_f32_bf16(const float* __restrict__ in,
                                                     __hip_bfloat16* __restrict__ out, int n) {
    int i = (blockIdx.x * 256 + threadIdx.x) << 2;
    if (i < n) {
        float4 v = *(const float4*)(in + i);
        ushort4 o = {f2u(v.x), f2u(v.y), f2u(v.z), f2u(v.w)};
        *(ushort4*)(out + i) = o;
    }
}

// ---------------------------------------------------------------------------
// MFMA bf16 GEMM: C = A*Bw^T. 128x128, BK=32, 4 waves 2x2, 4x4 16x16x32.
// EPI=1: qkv epilogue (w0: q~=fmap*0.125, w1: k~=fmap, w2: v) to natural
// [M,3072] bf16, PLUS K~^T (w1) and V^T (w2) as [(b*16+h)*64+d][4096] bf16.
// EPI=0: plain f32 store.
// ---------------------------------------------------------------------------
template<int EPI>
__global__ __launch_bounds__(256) void gemm_mfma(const __bf16* __restrict__ A,
                                                 const __bf16* __restrict__ Bw,
                                                 void* __restrict__ Cv,
                                                 __hip_bfloat16* __restrict__ KT,
                                                 __hip_bfloat16* __restrict__ VT,
                                                 int M, int N, int K) {
    __shared__ alignas(16) __bf16 As[128 * 32];
    __shared__ alignas(16) __bf16 Bs[128 * 32];
    const int tid = threadIdx.x;
    const int wave = tid >> 6, lane = tid & 63;
    const int wm = wave >> 1, wn = wave & 1;
    const int lq = lane >> 4, lr = lane & 15;
    const int m0 = blockIdx.y * 128, n0 = blockIdx.x * 128;

    f32x4 acc[4][4];
#pragma unroll
    for (int i = 0; i < 4; ++i)
#pragma unroll
        for (int j = 0; j < 4; ++j) acc[i][j] = (f32x4){0.f, 0.f, 0.f, 0.f};

    const int stg_r = lane >> 2, stg_c = (lane & 3) << 3;
    const __bf16* Ag0 = A + (size_t)(m0 + (wave << 4) + stg_r) * K + stg_c;
    const __bf16* Ag1 = A + (size_t)(m0 + 64 + (wave << 4) + stg_r) * K + stg_c;
    const __bf16* Bg0 = Bw + (size_t)(n0 + (wave << 4) + stg_r) * K + stg_c;
    const __bf16* Bg1 = Bw + (size_t)(n0 + 64 + (wave << 4) + stg_r) * K + stg_c;
    __bf16* Al0 = As + (wave << 9);
    __bf16* Al1 = As + ((wave + 4) << 9);
    __bf16* Bl0 = Bs + (wave << 9);
    __bf16* Bl1 = Bs + ((wave + 4) << 9);

    for (int kt = 0; kt < K; kt += 32) {
        __syncthreads();
        async16(Ag0 + kt, Al0);
        async16(Ag1 + kt, Al1);
        async16(Bg0 + kt, Bl0);
        async16(Bg1 + kt, Bl1);
        __syncthreads();
        bf16x8 af[4], bfr[4];
#pragma unroll
        for (int t = 0; t < 4; ++t) {
            af[t]  = *(const bf16x8*)&As[((wm << 6) + (t << 4) + lr) * 32 + (lq << 3)];
            bfr[t] = *(const bf16x8*)&Bs[((wn << 6) + (t << 4) + lr) * 32 + (lq << 3)];
        }
#pragma unroll
        for (int mt = 0; mt < 4; ++mt)
#pragma unroll
            for (int nt = 0; nt < 4; ++nt)
                acc[mt][nt] = __builtin_amdgcn_mfma_f32_16x16x32_bf16(
                    af[mt], bfr[nt], acc[mt][nt], 0, 0, 0);
    }

#pragma unroll
    for (int mt = 0; mt < 4; ++mt) {
#pragma unroll
        for (int nt = 0; nt < 4; ++nt) {
            int m = m0 + (wm << 6) + (mt << 4) + (lq << 2);
            int n = n0 + (wn << 6) + (nt << 4) + lr;
            if (EPI == 1) {
                int w = n >> 10, hh = (n >> 6) & 15, dd = n & 63;
                float vv[4];
#pragma unroll
                for (int r = 0; r < 4; ++r) {
                    float v = acc[mt][nt][r];
                    if (w == 0)      v = fmap1(v) * 0.125f;
                    else if (w == 1) v = fmap1(v);
                    vv[r] = v;
                    ((__hip_bfloat16*)Cv)[(size_t)(m + r) * N + n] = __float2bfloat16(v);
                }
                if (w >= 1) {   // transposed copies: w1 -> KT, w2 -> VT
                    int b = m >> 12, l = m & 4095;
                    __hip_bfloat16* T = (w == 1) ? KT : VT;
                    ushort4 u = {f2u(vv[0]), f2u(vv[1]), f2u(vv[2]), f2u(vv[3])};
                    *(ushort4*)&T[((size_t)((b * 16 + hh) * 64 + dd) << 12) + l] = u;
                }
            } else {
#pragma unroll
                for (int r = 0; r < 4; ++r)
                    ((float*)Cv)[(size_t)(m + r) * N + n] = acc[mt][nt][r];
            }
        }
    }
}

// ---------------------------------------------------------------------------
// MFMA per-chunk state: S_T[e][d] = sum_l VT[e][l]*KT[d][l]; Z[d] = sum_l KT[d][l].
// grid (16, 32); wave = chunk c = bx*4+w. Stores bf16.
// ---------------------------------------------------------------------------
__global__ __launch_bounds__(256) void chunk_state_mfma(const __hip_bfloat16* __restrict__ KTh,
                                                        const __hip_bfloat16* __restrict__ VTh,
                                                        __hip_bfloat16* __restrict__ Sb,
                                                        __hip_bfloat16* __restrict__ Zb) {
    const int tid = threadIdx.x, wave = tid >> 6, lane = tid & 63;
    const int quad = lane >> 4, lr = lane & 15;
    const int bh = blockIdx.y;
    const int c = blockIdx.x * 4 + wave;
    const __bf16* KT = (const __bf16*)KTh;
    const __bf16* VT = (const __bf16*)VTh;

    bf16x8 vt[4][2], kt[4][2];
#pragma unroll
    for (int t = 0; t < 4; ++t)
#pragma unroll
        for (int kk = 0; kk < 2; ++kk) {
            size_t rowoff = ((size_t)(bh * 64 + t * 16 + lr) << 12) + c * CK_ + kk * 32 + quad * 8;
            vt[t][kk] = *(const bf16x8*)&VT[rowoff];
            kt[t][kk] = *(const bf16x8*)&KT[rowoff];
        }

    U8 of;
#pragma unroll
    for (int j = 0; j < 8; ++j) of.e[j] = f2b(1.0f);

    __hip_bfloat16* Sp = Sb + ((size_t)(c * 32 + bh) << 12);
#pragma unroll
    for (int es = 0; es < 4; ++es) {
#pragma unroll
        for (int dt = 0; dt < 4; ++dt) {
            f32x4 acc = (f32x4){0.f, 0.f, 0.f, 0.f};
            acc = __builtin_amdgcn_mfma_f32_16x16x32_bf16(vt[es][0], kt[dt][0], acc, 0, 0, 0);
            acc = __builtin_amdgcn_mfma_f32_16x16x32_bf16(vt[es][1], kt[dt][1], acc, 0, 0, 0);
            // D[m=e][n=d]: col=lr -> d, row=quad*4+r -> e
#pragma unroll
            for (int r = 0; r < 4; ++r)
                Sp[(es * 16 + quad * 4 + r) * 64 + dt * 16 + lr] =
                    __float2bfloat16(acc[r]);
        }
    }
    // Z[d]: A=KT frag, B=ones -> D[m=d][n] (all n equal)
#pragma unroll
    for (int dt = 0; dt < 4; ++dt) {
        f32x4 z = (f32x4){0.f, 0.f, 0.f, 0.f};
        z = __builtin_amdgcn_mfma_f32_16x16x32_bf16(kt[dt][0], of.v, z, 0, 0, 0);
        z = __builtin_amdgcn_mfma_f32_16x16x32_bf16(kt[dt][1], of.v, z, 0, 0, 0);
        if (lr == 0) {
#pragma unroll
            for (int r = 0; r < 4; ++r)
                Zb[((c * 32 + bh) << 6) + dt * 16 + quad * 4 + r] = __float2bfloat16(z[r]);
        }
    }
}

// ---------------------------------------------------------------------------
// In-place exclusive prefix over 64 chunks on bf16 states, f32 carry.
// grid (16, 32).
// ---------------------------------------------------------------------------
__global__ __launch_bounds__(256) void prefix64(__hip_bfloat16* __restrict__ Sb,
                                                __hip_bfloat16* __restrict__ Zb) {
    const int bh = blockIdx.y;
    const int idx = blockIdx.x * 256 + threadIdx.x;   // 0..4095
    float run = 0.f;
    for (int c = 0; c < NC_; ++c) {
        size_t off = ((size_t)(c * 32 + bh) << 12) + idx;
        float cur = __bfloat162float(Sb[off]);
        Sb[off] = __float2bfloat16(run);
        run += cur;
    }
    if (blockIdx.x == 0 && threadIdx.x < 64) {
        float zr = 0.f;
        for (int c = 0; c < NC_; ++c) {
            int zoff = ((c * 32 + bh) << 6) + threadIdx.x;
            float cz = __bfloat162float(Zb[zoff]);
            Zb[zoff] = __float2bfloat16(zr);
            zr += cz;
        }
    }
}

// ---------------------------------------------------------------------------
// MFMA attention output (R8-verified structure; S/Z now bf16 vector loads).
// ---------------------------------------------------------------------------
__global__ __launch_bounds__(256) void attn_out_mfma(const __hip_bfloat16* __restrict__ qvh,
                                                     const __hip_bfloat16* __restrict__ Sbh,
                                                     const __hip_bfloat16* __restrict__ Zbh,
                                                     const __hip_bfloat16* __restrict__ VTh,
                                                     __hip_bfloat16* __restrict__ attn) {
    __shared__ __bf16 Pbuf[4 * 64 * 68];
    const int tid = threadIdx.x, wave = tid >> 6, lane = tid & 63;
    const int quad = lane >> 4, lr = lane & 15;
    const int bh = blockIdx.y, b = bh >> 4, h = bh & 15;
    const int c = blockIdx.x * 4 + wave;
    const size_t t0 = (size_t)b * L_ + c * CK_;
    const __bf16* qb = (const __bf16*)qvh;
    const __bf16* Sb = (const __bf16*)Sbh;
    const __bf16* Zb = (const __bf16*)Zbh;
    const __bf16* VT = (const __bf16*)VTh;
    __bf16* P = Pbuf + wave * (64 * 68);

    bf16x8 qf[4][2];
#pragma unroll
    for (int ls = 0; ls < 4; ++ls)
#pragma unroll
        for (int kk = 0; kk < 2; ++kk)
            qf[ls][kk] = *(const bf16x8*)&qb[(t0 + ls * 16 + lr) * 3072 + h * 64 + kk * 32 + quad * 8];

    f32x4 num[4][4], den[4];
#pragma unroll
    for (int i = 0; i < 4; ++i) {
        den[i] = (f32x4){0.f, 0.f, 0.f, 0.f};
#pragma unroll
        for (int j = 0; j < 4; ++j) num[i][j] = (f32x4){0.f, 0.f, 0.f, 0.f};
    }

    // den init: B[n][k=d] = Zp[d]
    bf16x8 zf[2];
#pragma unroll
    for (int kk = 0; kk < 2; ++kk)
        zf[kk] = *(const bf16x8*)&Zb[((size_t)(c * 32 + bh) << 6) + kk * 32 + quad * 8];
#pragma unroll
    for (int ls = 0; ls < 4; ++ls)
#pragma unroll
        for (int kk = 0; kk < 2; ++kk)
            den[ls] = __builtin_amdgcn_mfma_f32_16x16x32_bf16(qf[ls][kk], zf[kk], den[ls], 0, 0, 0);

    // num init: Q @ Spre  (B[e][k=d] = S_T[e][d] bf16)
#pragma unroll
    for (int es = 0; es < 4; ++es) {
        bf16x8 sf[2];
#pragma unroll
        for (int kk = 0; kk < 2; ++kk)
            sf[kk] = *(const bf16x8*)&Sb[((size_t)(c * 32 + bh) << 12)
                                         + (es * 16 + lr) * 64 + kk * 32 + quad * 8];
#pragma unroll
        for (int ls = 0; ls < 4; ++ls)
#pragma unroll
            for (int kk = 0; kk < 2; ++kk)
                num[ls][es] = __builtin_amdgcn_mfma_f32_16x16x32_bf16(
                    qf[ls][kk], sf[kk], num[ls][es], 0, 0, 0);
    }

    bf16x8 kf[4][2];
#pragma unroll
    for (int ms = 0; ms < 4; ++ms)
#pragma unroll
        for (int kk = 0; kk < 2; ++kk)
            kf[ms][kk] = *(const bf16x8*)&qb[(t0 + ms * 16 + lr) * 3072 + 1024 + h * 64 + kk * 32 + quad * 8];

    // P^T = K·Q^T -> D[m][l]; transpose-store natural P[l][m] packed b64.
#pragma unroll
    for (int ls = 0; ls < 4; ++ls) {
#pragma unroll
        for (int ms = 0; ms < 4; ++ms) {
            int off = (ls * 16 + lr) * 68 + ms * 16 + quad * 4;
            if (ms <= ls) {
                f32x4 pt = (f32x4){0.f, 0.f, 0.f, 0.f};
                pt = __builtin_amdgcn_mfma_f32_16x16x32_bf16(kf[ms][0], qf[ls][0], pt, 0, 0, 0);
                pt = __builtin_amdgcn_mfma_f32_16x16x32_bf16(kf[ms][1], qf[ls][1], pt, 0, 0, 0);
                ushort4 u;
                if (ms == ls) {
                    u.x = (quad * 4 + 0 > lr) ? 0 : f2u(pt[0]);
                    u.y = (quad * 4 + 1 > lr) ? 0 : f2u(pt[1]);
                    u.z = (quad * 4 + 2 > lr) ? 0 : f2u(pt[2]);
                    u.w = (quad * 4 + 3 > lr) ? 0 : f2u(pt[3]);
                } else {
                    u = (ushort4){f2u(pt[0]), f2u(pt[1]), f2u(pt[2]), f2u(pt[3])};
                }
                *(ushort4*)&P[off] = u;
            } else {
                *(ushort4*)&P[off] = (ushort4){0, 0, 0, 0};
            }
        }
    }

    U8 of;
#pragma unroll
    for (int j = 0; j < 8; ++j) of.e[j] = f2b(1.0f);

#pragma unroll
    for (int kk = 0; kk < 2; ++kk) {
        U8 pf[4];
#pragma unroll
        for (int ls = 0; ls < 4; ++ls) {
            pf[ls].half2[0] = *(const bf16x4*)&P[(ls * 16 + lr) * 68 + kk * 32 + quad * 8];
            pf[ls].half2[1] = *(const bf16x4*)&P[(ls * 16 + lr) * 68 + kk * 32 + quad * 8 + 4];
        }
        bf16x8 vf[4];
#pragma unroll
        for (int es = 0; es < 4; ++es)
            vf[es] = *(const bf16x8*)&VT[((size_t)((b * 16 + h) * 64 + es * 16 + lr) << 12)
                                         + c * CK_ + kk * 32 + quad * 8];
#pragma unroll
        for (int ls = 0; ls < 4; ++ls) {
            den[ls] = __builtin_amdgcn_mfma_f32_16x16x32_bf16(pf[ls].v, of.v, den[ls], 0, 0, 0);
#pragma unroll
            for (int es = 0; es < 4; ++es)
                num[ls][es] = __builtin_amdgcn_mfma_f32_16x16x32_bf16(
                    pf[ls].v, vf[es], num[ls][es], 0, 0, 0);
        }
    }

#pragma unroll
    for (int ls = 0; ls < 4; ++ls) {
#pragma unroll
        for (int r = 0; r < 4; ++r) {
            float inv = 1.f / fmaxf(den[ls][r], 1e-6f);
            size_t row = (t0 + ls * 16 + quad * 4 + r) * 1024 + h * 64;
#pragma unroll
            for (int es = 0; es < 4; ++es)
                attn[row + es * 16 + lr] = __float2bfloat16(num[ls][es][r] * inv);
        }
    }
}

// ---------------------------------------------------------------------------
extern "C" void kernel_launch(void* const* d_in, const int* in_sizes, int n_in,
                              void* d_out, int out_size, void* d_ws, size_t ws_size,
                              hipStream_t stream) {
    (void)ws_size; (void)out_size;
    const float *x = nullptr, *Wqkv = nullptr, *Wout = nullptr;
    for (int i = 0; i < n_in; ++i) {
        if (in_sizes[i] == 8388608)      x    = (const float*)d_in[i];
        else if (in_sizes[i] == 3145728) Wqkv = (const float*)d_in[i];
        else if (in_sizes[i] == 1048576) Wout = (const float*)d_in[i];
    }

    // ws (bf16 elems): 126.1 MB total (< 142.7 MB known-good).
    __hip_bfloat16* ws16  = (__hip_bfloat16*)d_ws;
    __hip_bfloat16* xb    = ws16;                       //  8388608 (attn aliases)
    __hip_bfloat16* attn  = ws16;
    __hip_bfloat16* Wqkvb = ws16 + 8388608;             //  3145728
    __hip_bfloat16* Woutb = Wqkvb + 3145728;            //  1048576
    __hip_bfloat16* qv    = Woutb + 1048576;            // 25165824
    __hip_bfloat16* VT    = qv + 25165824;              //  8388608
    __hip_bfloat16* KT    = VT + 8388608;               //  8388608
    __hip_bfloat16* Sb    = KT + 8388608;               //  8388608
    __hip_bfloat16* Zb    = Sb + 8388608;               //   131072

    cast_f32_bf16<<<8388608 / 1024, 256, 0, stream>>>(x, xb, 8388608);
    cast_f32_bf16<<<3145728 / 1024, 256, 0, stream>>>(Wqkv, Wqkvb, 3145728);
    cast_f32_bf16<<<1048576 / 1024, 256, 0, stream>>>(Wout, Woutb, 1048576);

    // 1. qv (+KT,+VT) = feature_map(xb @ Wqkvb^T)
    gemm_mfma<1><<<dim3(3072 / 128, 8192 / 128), 256, 0, stream>>>(
        (const __bf16*)xb, (const __bf16*)Wqkvb, qv, KT, VT, B_ * L_, 3 * E_, E_);
    // 2. per-chunk states via MFMA (bf16 out)
    chunk_state_mfma<<<dim3(16, B_ * H_), 256, 0, stream>>>(KT, VT, Sb, Zb);
    // 3. exclusive prefix over 64 chunks (in-place bf16, f32 carry)
    prefix64<<<dim3(16, B_ * H_), 256, 0, stream>>>(Sb, Zb);
    // 4. MFMA attention output -> attn bf16
    attn_out_mfma<<<dim3(16, B_ * H_), 256, 0, stream>>>(qv, Sb, Zb, VT, attn);
    // 5. out = attn @ Woutb^T, f32
    gemm_mfma<0><<<dim3(1024 / 128, 8192 / 128), 256, 0, stream>>>(
        (const __bf16*)attn, (const __bf16*)Woutb, d_out, nullptr, nullptr, B_ * L_, E_, E_);
}